// Round 4
// baseline (5415.480 us; speedup 1.0000x reference)
//
#include <hip/hip_runtime.h>

// LightGCN encoder, round 4 — identical to round 3 (round-3 run hit a GPU
// acquisition timeout; the kernel never executed).
//
// Destination-binned SpMM with LDS accumulation:
// Round-1 evidence: global fp32 atomics thrash L2 (WRITE_SIZE == NNZ*256B ->
// every atomic write reached HBM; FETCH 781MB from RMW refetch). Fix: bin the
// 4.8M edges by destination-row bucket (128 rows/bucket -> 32KB LDS tile),
// accumulate per-bucket in LDS (ds_add_f32, lane=dim, conflict-free), write
// each output row exactly once, fuse acc += 0.25*h into the write-out.

#define USER_NUM 100000
#define ITEM_NUM 50000
#define N_NODES (USER_NUM + ITEM_NUM)
#define EMB 64
#define NFLOAT (N_NODES * EMB)        // 9,600,000 floats
#define USER_FLOATS (USER_NUM * EMB)

#define SHIFT 7
#define BROWS 128                      // rows per bucket
#define NB ((N_NODES + BROWS - 1) / BROWS)   // 1172 buckets
#define COLMASK 0x3FFFF                // col < 150000 < 2^18

// ---------------- init: h0 = ego, acc = 0.25*ego ----------------
__global__ __launch_bounds__(256) void lgcn_init(const float* __restrict__ user,
                                                 const float* __restrict__ item,
                                                 float* __restrict__ h,
                                                 float* __restrict__ acc) {
    const int total4 = NFLOAT / 4;
    const int user4 = USER_FLOATS / 4;
    int stride = gridDim.x * blockDim.x;
    for (int i = blockIdx.x * blockDim.x + threadIdx.x; i < total4; i += stride) {
        float4 v = (i < user4) ? reinterpret_cast<const float4*>(user)[i]
                               : reinterpret_cast<const float4*>(item)[i - user4];
        reinterpret_cast<float4*>(h)[i] = v;
        reinterpret_cast<float4*>(acc)[i] =
            make_float4(v.x * 0.25f, v.y * 0.25f, v.z * 0.25f, v.w * 0.25f);
    }
}

// ---------------- preprocess: histogram over destination buckets ----------------
__global__ __launch_bounds__(256) void lgcn_hist(const int* __restrict__ row,
                                                 int* __restrict__ ghist, int nnz) {
    __shared__ int cnt[NB];
    for (int t = threadIdx.x; t < NB; t += 256) cnt[t] = 0;
    __syncthreads();
    int stride = gridDim.x * blockDim.x;
    for (int i = blockIdx.x * blockDim.x + threadIdx.x; i < nnz; i += stride)
        atomicAdd(&cnt[row[i] >> SHIFT], 1);
    __syncthreads();
    for (int t = threadIdx.x; t < NB; t += 256) {
        int c = cnt[t];
        if (c) atomicAdd(&ghist[t], c);
    }
}

// ---------------- preprocess: exclusive scan (single block) ----------------
__global__ __launch_bounds__(256) void lgcn_scan2(const int* __restrict__ ghist,
                                                  int* __restrict__ bstart,
                                                  int* __restrict__ cursor, int nnz) {
    __shared__ int buf[NB];
    for (int t = threadIdx.x; t < NB; t += 256) buf[t] = ghist[t];
    __syncthreads();
    if (threadIdx.x == 0) {
        int run = 0;
        for (int b = 0; b < NB; ++b) { int c = buf[b]; buf[b] = run; run += c; }
    }
    __syncthreads();
    for (int t = threadIdx.x; t < NB; t += 256) {
        bstart[t] = buf[t];
        cursor[t] = buf[t];
    }
    if (threadIdx.x == 0) bstart[NB] = nnz;
}

// ---------------- preprocess: scatter edges into buckets ----------------
#define SC_EPT 32            // edges per thread
#define SC_CHUNK (256 * SC_EPT)
__global__ __launch_bounds__(256) void lgcn_scatter(const int* __restrict__ row,
                                                    const int* __restrict__ col,
                                                    const float* __restrict__ vals,
                                                    int* __restrict__ cursor,
                                                    uint2* __restrict__ bkv, int nnz) {
    __shared__ int cnt[NB];
    __shared__ int base[NB];
    for (int t = threadIdx.x; t < NB; t += 256) cnt[t] = 0;
    __syncthreads();
    long long start = (long long)blockIdx.x * SC_CHUNK;
    for (int k = 0; k < SC_EPT; ++k) {
        long long i = start + k * 256 + threadIdx.x;
        if (i < nnz) atomicAdd(&cnt[row[i] >> SHIFT], 1);
    }
    __syncthreads();
    for (int t = threadIdx.x; t < NB; t += 256) {
        int c = cnt[t];
        base[t] = c ? atomicAdd(&cursor[t], c) : 0;
    }
    __syncthreads();
    for (int t = threadIdx.x; t < NB; t += 256) cnt[t] = 0;
    __syncthreads();
    for (int k = 0; k < SC_EPT; ++k) {
        long long i = start + k * 256 + threadIdx.x;
        if (i < nnz) {
            int r = row[i];
            int b = r >> SHIFT;
            int l = atomicAdd(&cnt[b], 1);
            int pos = base[b] + l;
            bkv[pos] = make_uint2(((unsigned)(r & (BROWS - 1)) << 18) | (unsigned)col[i],
                                  __float_as_uint(vals[i]));
        }
    }
}

// ---------------- binned SpMM: one bucket per block ----------------
// 512 threads = 8 waves, one edge per wave, lane = embedding dim.
// LDS atomic adds: 64 lanes over 32 banks -> 2 lanes/bank, free on CDNA4 (m136).
template <bool LAST>
__global__ __launch_bounds__(512) void lgcn_spmm_binned(const uint2* __restrict__ bkv,
                                                        const int* __restrict__ bstart,
                                                        const float* __restrict__ x,
                                                        float* __restrict__ h_next,
                                                        float* __restrict__ acc) {
    __shared__ float smem[BROWS * EMB];   // 32 KB
    float4* s4 = reinterpret_cast<float4*>(smem);
    const int tid = threadIdx.x;
    const int lane = tid & 63;
    const int wid = tid >> 6;
    const int b = blockIdx.x;

    for (int t = tid; t < BROWS * EMB / 4; t += 512)
        s4[t] = make_float4(0.f, 0.f, 0.f, 0.f);
    __syncthreads();

    const int s = bstart[b], e = bstart[b + 1];
    for (int i = s + wid; i < e; i += 8) {
        uint2 kv = bkv[i];                         // wave-uniform broadcast
        int c = kv.x & COLMASK;
        int lr = kv.x >> 18;
        float v = __uint_as_float(kv.y);
        float xv = x[(size_t)c * EMB + lane];      // coalesced 256B gather
        atomicAdd(&smem[lr * EMB + lane], v * xv); // ds_add_f32
    }
    __syncthreads();

    const int nrows = min(BROWS, N_NODES - b * BROWS);
    const int nq = nrows * (EMB / 4);
    const size_t gbase = (size_t)b * BROWS * (EMB / 4);
    float4* h4 = reinterpret_cast<float4*>(h_next);
    float4* a4 = reinterpret_cast<float4*>(acc);
    for (int t = tid; t < nq; t += 512) {
        float4 v = s4[t];
        if (!LAST) h4[gbase + t] = v;
        float4 a = a4[gbase + t];
        a.x += 0.25f * v.x; a.y += 0.25f * v.y;
        a.z += 0.25f * v.z; a.w += 0.25f * v.w;
        a4[gbase + t] = a;
    }
}

extern "C" void kernel_launch(void* const* d_in, const int* in_sizes, int n_in,
                              void* d_out, int out_size, void* d_ws, size_t ws_size,
                              hipStream_t stream) {
    const float* user_emb = (const float*)d_in[0];
    const float* item_emb = (const float*)d_in[1];
    const int* adj_row = (const int*)d_in[2];
    const int* adj_col = (const int*)d_in[3];
    const float* adj_vals = (const float*)d_in[4];
    const int nnz = in_sizes[2];

    float* acc = (float*)d_out;

    char* ws = (char*)d_ws;
    float* h0 = (float*)ws;                      ws += (size_t)NFLOAT * 4;
    float* h1 = (float*)ws;                      ws += (size_t)NFLOAT * 4;
    uint2* bkv = (uint2*)ws;                     ws += (size_t)nnz * 8;
    int* ghist = (int*)ws;                       ws += (size_t)NB * 4;
    int* bstart = (int*)ws;                      ws += (size_t)(NB + 1) * 4;
    int* cursor = (int*)ws;                      ws += (size_t)NB * 4;

    // --- preprocess: bin edges by destination bucket (reused for all 3 layers)
    hipMemsetAsync(ghist, 0, (size_t)NB * 4, stream);
    lgcn_hist<<<512, 256, 0, stream>>>(adj_row, ghist, nnz);
    lgcn_scan2<<<1, 256, 0, stream>>>(ghist, bstart, cursor, nnz);
    int sc_blocks = (nnz + SC_CHUNK - 1) / SC_CHUNK;
    lgcn_scatter<<<sc_blocks, 256, 0, stream>>>(adj_row, adj_col, adj_vals,
                                                cursor, bkv, nnz);

    // --- init: h0 = ego, acc = 0.25*ego
    lgcn_init<<<2048, 256, 0, stream>>>(user_emb, item_emb, h0, acc);

    // --- 3 propagation layers, acc fused into write-out
    lgcn_spmm_binned<false><<<NB, 512, 0, stream>>>(bkv, bstart, h0, h1, acc);
    lgcn_spmm_binned<false><<<NB, 512, 0, stream>>>(bkv, bstart, h1, h0, acc);
    lgcn_spmm_binned<true><<<NB, 512, 0, stream>>>(bkv, bstart, h0, nullptr, acc);
}

// Round 5
// 878.143 us; speedup vs baseline: 6.1670x; 6.1670x over previous
//
#include <hip/hip_runtime.h>

// LightGCN encoder, round 5: pull-based CSR SpMM.
//
// Round-4 post-mortem: binned LDS-atomic SpMM was latency-bound (HBM 5%,
// VALU 4%, occ 60%): one dependent bkv->gather chain per wave (no MLP) plus
// a 1172-block residency tail. Fix: build full row-sorted CSR (bucket scatter
// + per-bucket counting sort, all coalesced), then SpMM = one wave per output
// row: lane-parallel edge staging, shfl-broadcast (col,val), gathers unrolled
// 8-deep, accumulate in one VGPR (lane = dim), single coalesced row write
// with fused acc += 0.25*h. No atomics, no memset, 150k independent waves.

#define USER_NUM 100000
#define ITEM_NUM 50000
#define N_NODES (USER_NUM + ITEM_NUM)
#define EMB 64
#define NFLOAT (N_NODES * EMB)        // 9,600,000 floats
#define USER_FLOATS (USER_NUM * EMB)

#define SHIFT 7
#define BROWS 128                      // rows per bucket
#define NB ((N_NODES + BROWS - 1) / BROWS)   // 1172 buckets
#define COLMASK 0x3FFFF                // col < 150000 < 2^18

// ---------------- init: h0 = ego, acc = 0.25*ego ----------------
__global__ __launch_bounds__(256) void lgcn_init(const float* __restrict__ user,
                                                 const float* __restrict__ item,
                                                 float* __restrict__ h,
                                                 float* __restrict__ acc) {
    const int total4 = NFLOAT / 4;
    const int user4 = USER_FLOATS / 4;
    int stride = gridDim.x * blockDim.x;
    for (int i = blockIdx.x * blockDim.x + threadIdx.x; i < total4; i += stride) {
        float4 v = (i < user4) ? reinterpret_cast<const float4*>(user)[i]
                               : reinterpret_cast<const float4*>(item)[i - user4];
        reinterpret_cast<float4*>(h)[i] = v;
        reinterpret_cast<float4*>(acc)[i] =
            make_float4(v.x * 0.25f, v.y * 0.25f, v.z * 0.25f, v.w * 0.25f);
    }
}

// ---------------- preprocess: histogram over destination buckets ----------------
__global__ __launch_bounds__(256) void lgcn_hist(const int* __restrict__ row,
                                                 int* __restrict__ ghist, int nnz) {
    __shared__ int cnt[NB];
    for (int t = threadIdx.x; t < NB; t += 256) cnt[t] = 0;
    __syncthreads();
    int stride = gridDim.x * blockDim.x;
    for (int i = blockIdx.x * blockDim.x + threadIdx.x; i < nnz; i += stride)
        atomicAdd(&cnt[row[i] >> SHIFT], 1);
    __syncthreads();
    for (int t = threadIdx.x; t < NB; t += 256) {
        int c = cnt[t];
        if (c) atomicAdd(&ghist[t], c);
    }
}

// ---------------- preprocess: exclusive scan over buckets (single block) ----------------
__global__ __launch_bounds__(256) void lgcn_scan2(const int* __restrict__ ghist,
                                                  int* __restrict__ bstart,
                                                  int* __restrict__ cursor, int nnz) {
    __shared__ int buf[NB];
    for (int t = threadIdx.x; t < NB; t += 256) buf[t] = ghist[t];
    __syncthreads();
    if (threadIdx.x == 0) {
        int run = 0;
        for (int b = 0; b < NB; ++b) { int c = buf[b]; buf[b] = run; run += c; }
    }
    __syncthreads();
    for (int t = threadIdx.x; t < NB; t += 256) {
        bstart[t] = buf[t];
        cursor[t] = buf[t];
    }
    if (threadIdx.x == 0) bstart[NB] = nnz;
}

// ---------------- preprocess: scatter edges into buckets ----------------
#define SC_EPT 32
#define SC_CHUNK (256 * SC_EPT)
__global__ __launch_bounds__(256) void lgcn_scatter(const int* __restrict__ row,
                                                    const int* __restrict__ col,
                                                    const float* __restrict__ vals,
                                                    int* __restrict__ cursor,
                                                    uint2* __restrict__ bkv_tmp, int nnz) {
    __shared__ int cnt[NB];
    __shared__ int base[NB];
    for (int t = threadIdx.x; t < NB; t += 256) cnt[t] = 0;
    __syncthreads();
    long long start = (long long)blockIdx.x * SC_CHUNK;
    for (int k = 0; k < SC_EPT; ++k) {
        long long i = start + k * 256 + threadIdx.x;
        if (i < nnz) atomicAdd(&cnt[row[i] >> SHIFT], 1);
    }
    __syncthreads();
    for (int t = threadIdx.x; t < NB; t += 256) {
        int c = cnt[t];
        base[t] = c ? atomicAdd(&cursor[t], c) : 0;
    }
    __syncthreads();
    for (int t = threadIdx.x; t < NB; t += 256) cnt[t] = 0;
    __syncthreads();
    for (int k = 0; k < SC_EPT; ++k) {
        long long i = start + k * 256 + threadIdx.x;
        if (i < nnz) {
            int r = row[i];
            int b = r >> SHIFT;
            int l = atomicAdd(&cnt[b], 1);
            int pos = base[b] + l;
            bkv_tmp[pos] = make_uint2(((unsigned)(r & (BROWS - 1)) << 18) | (unsigned)col[i],
                                      __float_as_uint(vals[i]));
        }
    }
}

// ---------------- preprocess: per-bucket counting sort -> CSR + rowptr ----------------
// One block per bucket. Two coalesced global reads of the bucket; scatter
// write stays within the bucket's 32KB span (L2-resident).
__global__ __launch_bounds__(256) void lgcn_sort(const uint2* __restrict__ bkv_tmp,
                                                 const int* __restrict__ bstart,
                                                 uint2* __restrict__ bkv,
                                                 int* __restrict__ rowptr, int nnz) {
    __shared__ int cnt[BROWS];
    __shared__ int startsh[BROWS];
    const int b = blockIdx.x;
    const int s = bstart[b], e = bstart[b + 1];
    for (int t = threadIdx.x; t < BROWS; t += 256) cnt[t] = 0;
    __syncthreads();
    for (int i = s + threadIdx.x; i < e; i += 256)
        atomicAdd(&cnt[bkv_tmp[i].x >> 18], 1);
    __syncthreads();
    if (threadIdx.x == 0) {
        int run = s;
        for (int j = 0; j < BROWS; ++j) { int c = cnt[j]; startsh[j] = run; run += c; }
    }
    __syncthreads();
    const int grow0 = b * BROWS;
    for (int t = threadIdx.x; t < BROWS; t += 256) {
        int gr = grow0 + t;
        if (gr < N_NODES) rowptr[gr] = startsh[t];
        cnt[t] = startsh[t];          // becomes the scatter cursor
    }
    if (b == NB - 1 && threadIdx.x == 0) rowptr[N_NODES] = nnz;
    __syncthreads();
    for (int i = s + threadIdx.x; i < e; i += 256) {
        uint2 kv = bkv_tmp[i];
        int lr = kv.x >> 18;
        int pos = atomicAdd(&cnt[lr], 1);
        bkv[pos] = make_uint2(kv.x & COLMASK, kv.y);  // store (col, valbits)
    }
}

// ---------------- pull SpMM: one wave per output row ----------------
// lane = embedding dim; acc in one VGPR; edges staged lane-parallel then
// shfl-broadcast; gathers issued 8-deep for MLP.
template <bool LAST>
__global__ __launch_bounds__(256) void lgcn_spmm_pull(const uint2* __restrict__ bkv,
                                                      const int* __restrict__ rowptr,
                                                      const float* __restrict__ x,
                                                      float* __restrict__ h_next,
                                                      float* __restrict__ acc) {
    const int lane = threadIdx.x & 63;
    const int wid = threadIdx.x >> 6;
    const int r = blockIdx.x * 4 + wid;
    if (r >= N_NODES) return;

    const int s = rowptr[r];
    const int deg = rowptr[r + 1] - s;
    const uint2* ebase = bkv + s;

    float a = 0.f;
    for (int base = 0; base < deg; base += 64) {
        int n = deg - base;
        if (n > 64) n = 64;
        uint2 kv = make_uint2(0u, 0u);
        if (lane < n) kv = ebase[base + lane];
        int k = 0;
        for (; k + 8 <= n; k += 8) {
            float xs0, xs1, xs2, xs3, xs4, xs5, xs6, xs7;
            float v0, v1, v2, v3, v4, v5, v6, v7;
            {
                int c; 
                c = __shfl((int)kv.x, k + 0); v0 = __uint_as_float(__shfl((int)kv.y, k + 0)); xs0 = x[(c << 6) + lane];
                c = __shfl((int)kv.x, k + 1); v1 = __uint_as_float(__shfl((int)kv.y, k + 1)); xs1 = x[(c << 6) + lane];
                c = __shfl((int)kv.x, k + 2); v2 = __uint_as_float(__shfl((int)kv.y, k + 2)); xs2 = x[(c << 6) + lane];
                c = __shfl((int)kv.x, k + 3); v3 = __uint_as_float(__shfl((int)kv.y, k + 3)); xs3 = x[(c << 6) + lane];
                c = __shfl((int)kv.x, k + 4); v4 = __uint_as_float(__shfl((int)kv.y, k + 4)); xs4 = x[(c << 6) + lane];
                c = __shfl((int)kv.x, k + 5); v5 = __uint_as_float(__shfl((int)kv.y, k + 5)); xs5 = x[(c << 6) + lane];
                c = __shfl((int)kv.x, k + 6); v6 = __uint_as_float(__shfl((int)kv.y, k + 6)); xs6 = x[(c << 6) + lane];
                c = __shfl((int)kv.x, k + 7); v7 = __uint_as_float(__shfl((int)kv.y, k + 7)); xs7 = x[(c << 6) + lane];
            }
            a = fmaf(v0, xs0, a); a = fmaf(v1, xs1, a);
            a = fmaf(v2, xs2, a); a = fmaf(v3, xs3, a);
            a = fmaf(v4, xs4, a); a = fmaf(v5, xs5, a);
            a = fmaf(v6, xs6, a); a = fmaf(v7, xs7, a);
        }
        for (; k < n; ++k) {
            int c = __shfl((int)kv.x, k);
            float v = __uint_as_float(__shfl((int)kv.y, k));
            a = fmaf(v, x[(c << 6) + lane], a);
        }
    }

    const int o = (r << 6) + lane;
    if (!LAST) h_next[o] = a;
    acc[o] += 0.25f * a;
}

extern "C" void kernel_launch(void* const* d_in, const int* in_sizes, int n_in,
                              void* d_out, int out_size, void* d_ws, size_t ws_size,
                              hipStream_t stream) {
    const float* user_emb = (const float*)d_in[0];
    const float* item_emb = (const float*)d_in[1];
    const int* adj_row = (const int*)d_in[2];
    const int* adj_col = (const int*)d_in[3];
    const float* adj_vals = (const float*)d_in[4];
    const int nnz = in_sizes[2];

    float* acc = (float*)d_out;

    char* ws = (char*)d_ws;
    float* h0 = (float*)ws;                       ws += (size_t)NFLOAT * 4;
    char* tmp_region = ws;                        ws += (size_t)NFLOAT * 4;
    uint2* bkv_tmp = (uint2*)tmp_region;          // dead after lgcn_sort
    float* h1 = (float*)tmp_region;               // reuses bkv_tmp's space
    uint2* bkv = (uint2*)ws;                      ws += (size_t)nnz * 8;
    int* rowptr = (int*)ws;                       ws += (size_t)(N_NODES + 1) * 4;
    int* ghist = (int*)ws;                        ws += (size_t)NB * 4;
    int* bstart = (int*)ws;                       ws += (size_t)(NB + 1) * 4;
    int* cursor = (int*)ws;                       ws += (size_t)NB * 4;

    // --- preprocess: bucket-bin, then counting-sort to row-sorted CSR
    hipMemsetAsync(ghist, 0, (size_t)NB * 4, stream);
    lgcn_hist<<<512, 256, 0, stream>>>(adj_row, ghist, nnz);
    lgcn_scan2<<<1, 256, 0, stream>>>(ghist, bstart, cursor, nnz);
    int sc_blocks = (nnz + SC_CHUNK - 1) / SC_CHUNK;
    lgcn_scatter<<<sc_blocks, 256, 0, stream>>>(adj_row, adj_col, adj_vals,
                                                cursor, bkv_tmp, nnz);
    lgcn_sort<<<NB, 256, 0, stream>>>(bkv_tmp, bstart, bkv, rowptr, nnz);

    // --- init: h0 = ego, acc = 0.25*ego
    lgcn_init<<<2048, 256, 0, stream>>>(user_emb, item_emb, h0, acc);

    // --- 3 propagation layers (pull), acc fused into write-out
    const int grid = (N_NODES + 3) / 4;   // one wave per row, 4 waves/block
    lgcn_spmm_pull<false><<<grid, 256, 0, stream>>>(bkv, rowptr, h0, h1, acc);
    lgcn_spmm_pull<false><<<grid, 256, 0, stream>>>(bkv, rowptr, h1, h0, acc);
    lgcn_spmm_pull<true><<<grid, 256, 0, stream>>>(bkv, rowptr, h0, nullptr, acc);
}